// Round 2
// baseline (2134.843 us; speedup 1.0000x reference)
//
#include <hip/hip_runtime.h>

// SparseConv2d: N=32, OC=IC=256, H=W=56, K=3, stride=1, pad=1, ~10% nnz weights
constexpr int NB  = 32;
constexpr int ICC = 256;
constexpr int OCC = 256;
constexpr int HH  = 56;
constexpr int WWW = 56;
constexpr int HW  = HH * WWW;     // 3136
constexpr int CHW = ICC * HW;     // 802816
constexpr int TAPS = ICC * 9;     // 2304
constexpr int CAP  = 704;         // nnz capacity per oc (mean ~230)
constexpr int XT = 14;            // x-tiles of 4
constexpr int YT = 14;            // y-tiles of 4

struct __attribute__((packed)) f4p { float4 v; };

__global__ __launch_bounds__(448) void sparse_conv_tile(
    const float* __restrict__ in, const float* __restrict__ w,
    const float* __restrict__ bias, const int* __restrict__ mask,
    float* __restrict__ out)
{
  const int oc  = blockIdx.x;   // oc fastest -> co-resident blocks share input slab
  const int yg  = blockIdx.y;   // y-tile: row-edge handling is block-uniform
  const int tid = threadIdx.x;

  __shared__ int2 s_tap[CAP];   // {meta, weight-bits}; meta = ((soff+57)<<6)|(kh<<2)|kw
  __shared__ int  s_wtot[7];
  __shared__ int  s_cnt;

  // ---- per-block compaction of this oc's nonzero taps (ordered by ic,kh,kw) ----
  {
    int c = 0;
    float wv[9]; int mk[9];
    #pragma unroll
    for (int j = 0; j < 9; ++j) { wv[j] = 0.f; mk[j] = 0; }
    if (tid < ICC) {
      const int base = oc * TAPS + tid * 9;
      #pragma unroll
      for (int j = 0; j < 9; ++j) {
        wv[j] = w[base + j]; mk[j] = mask[base + j];
        c += (mk[j] != 0) ? 1 : 0;
      }
    }
    const int lane = tid & 63, wvi = tid >> 6;
    int s = c;
    for (int d = 1; d < 64; d <<= 1) { int o = __shfl_up(s, d, 64); if (lane >= d) s += o; }
    if (lane == 63) s_wtot[wvi] = s;
    __syncthreads();
    int wbase = 0;
    for (int q = 0; q < wvi; ++q) wbase += s_wtot[q];
    int pos = wbase + s - c;                 // exclusive prefix over the block
    if (tid < ICC) {
      #pragma unroll
      for (int j = 0; j < 9; ++j) {
        if (mk[j] != 0) {
          const int kh = j / 3, kw = j - kh * 3;
          const int soff = tid * HW + (kh - 1) * WWW + (kw - 1);   // ic = tid
          s_tap[pos] = make_int2(((soff + 57) << 6) | (kh << 2) | kw,
                                 __float_as_int(wv[j]));
          ++pos;
        }
      }
      if (tid == ICC - 1) s_cnt = pos;       // inclusive total
    }
    __syncthreads();
  }

  const int nn = s_cnt;

  // thread -> 4x4 output tile: n in 0..31, xg in 0..13
  const int n  = tid / XT;
  const int xg = tid - n * XT;
  const int y0 = yg * 4, x0 = xg * 4;

  const int ibase = n * CHW + y0 * WWW + x0;
  const int obase = (n * OCC + oc) * HW + y0 * WWW + x0;
  const float bv = bias[oc];

  float4 a0 = {bv,bv,bv,bv}, a1 = {bv,bv,bv,bv}, a2 = {bv,bv,bv,bv}, a3 = {bv,bv,bv,bv};

  // x-edge masks: only col -1 (x0==0,kw==0,e==0) and col 56 (x0==52,kw==2,e==3) invalid
  const float fx0 = (xg == 0)      ? 0.f : 1.f;
  const float fx3 = (xg == XT - 1) ? 0.f : 1.f;

  const bool edge   = (yg == 0) || (yg == YT - 1);          // block-uniform
  const bool danger = (yg == 0      && n == 0      && xg == 0) ||
                      (yg == YT - 1 && n == NB - 1 && xg == XT - 1);

  if (!edge) {
    // interior: rows y0-1..y0+4 all valid, addresses in-bounds -> maskless rows
    #pragma unroll 2
    for (int j = 0; j < nn; ++j) {
      const int2  t   = s_tap[j];
      const int   m   = __builtin_amdgcn_readfirstlane(t.x);
      const float val = __uint_as_float(__builtin_amdgcn_readfirstlane((unsigned)t.y));
      const int soff = (m >> 6) - 57;        // ic*HW + (kh-1)*WWW + (kw-1), scalar
      const int kw   = m & 3;
      const float* p = in + (ibase + soff);
      const float4 v0 = ((const f4p*)(p          ))->v;
      const float4 v1 = ((const f4p*)(p +     WWW))->v;
      const float4 v2 = ((const f4p*)(p + 2 * WWW))->v;
      const float4 v3 = ((const f4p*)(p + 3 * WWW))->v;
      const float t0 = (kw == 0) ? val * fx0 : val;
      const float t3 = (kw == 2) ? val * fx3 : val;
      a0.x += t0 * v0.x; a0.y += val * v0.y; a0.z += val * v0.z; a0.w += t3 * v0.w;
      a1.x += t0 * v1.x; a1.y += val * v1.y; a1.z += val * v1.z; a1.w += t3 * v1.w;
      a2.x += t0 * v2.x; a2.y += val * v2.y; a2.z += val * v2.z; a2.w += t3 * v2.w;
      a3.x += t0 * v3.x; a3.y += val * v3.y; a3.z += val * v3.z; a3.w += t3 * v3.w;
    }
  } else if (!danger) {
    // y-edge blocks: per-row validity masks + clamped row addresses
    for (int j = 0; j < nn; ++j) {
      const int2  t   = s_tap[j];
      const int   m   = __builtin_amdgcn_readfirstlane(t.x);
      const float val = __uint_as_float(__builtin_amdgcn_readfirstlane((unsigned)t.y));
      const int soff = (m >> 6) - 57;
      const int kh   = (m >> 2) & 3;
      const int kw   = m & 3;
      #pragma unroll
      for (int r = 0; r < 4; ++r) {
        const int row = y0 + r + kh - 1;
        const bool ok = (unsigned)row < (unsigned)HH;
        const int off = ok ? (ibase + soff + r * WWW) : 0;
        const float4 v = ((const f4p*)(in + off))->v;
        const float va = ok ? val : 0.f;
        const float t0 = (kw == 0) ? va * fx0 : va;
        const float t3 = (kw == 2) ? va * fx3 : va;
        float4* ar = (r == 0) ? &a0 : (r == 1) ? &a1 : (r == 2) ? &a2 : &a3;
        ar->x += t0 * v.x; ar->y += va * v.y; ar->z += va * v.z; ar->w += t3 * v.w;
      }
    }
  } else {
    // buffer-boundary tiles (2 per oc): fully guarded scalar path
    for (int j = 0; j < nn; ++j) {
      const int2  t   = s_tap[j];
      const int   m   = t.x;
      const float val = __uint_as_float((unsigned)t.y);
      const int soff = (m >> 6) - 57;
      const int kh   = (m >> 2) & 3;
      const int kw   = m & 3;
      #pragma unroll
      for (int r = 0; r < 4; ++r) {
        const int row = y0 + r + kh - 1;
        const bool rok = (unsigned)row < (unsigned)HH;
        float4* ar = (r == 0) ? &a0 : (r == 1) ? &a1 : (r == 2) ? &a2 : &a3;
        #pragma unroll
        for (int e = 0; e < 4; ++e) {
          const int col = x0 + e + kw - 1;
          const bool ok = rok && ((unsigned)col < (unsigned)WWW);
          const int off = ok ? (ibase + soff + r * WWW + e) : 0;
          const float xv = in[off];
          const float tv = ok ? val : 0.f;
          if      (e == 0) ar->x += tv * xv;
          else if (e == 1) ar->y += tv * xv;
          else if (e == 2) ar->z += tv * xv;
          else             ar->w += tv * xv;
        }
      }
    }
  }

  *(float4*)(out + obase          ) = a0;
  *(float4*)(out + obase +     WWW) = a1;
  *(float4*)(out + obase + 2 * WWW) = a2;
  *(float4*)(out + obase + 3 * WWW) = a3;
}

extern "C" void kernel_launch(void* const* d_in, const int* in_sizes, int n_in,
                              void* d_out, int out_size, void* d_ws, size_t ws_size,
                              hipStream_t stream) {
  const float* in   = (const float*)d_in[0];
  const float* w    = (const float*)d_in[1];
  const float* bias = (const float*)d_in[2];
  const int*   mask = (const int*)d_in[3];
  float*       out  = (float*)d_out;

  dim3 grid(OCC, YT);        // oc fastest; 448 threads = 32 n x 14 xg, one 4x4 tile each
  sparse_conv_tile<<<grid, 448, 0, stream>>>(in, w, bias, mask, out);
}

// Round 3
// 1943.854 us; speedup vs baseline: 1.0983x; 1.0983x over previous
//
#include <hip/hip_runtime.h>

// SparseConv2d: N=32, OC=IC=256, H=W=56, K=3, stride=1, pad=1, ~10% nnz weights
constexpr int NB  = 32;
constexpr int ICC = 256;
constexpr int OCC = 256;
constexpr int HH  = 56;
constexpr int WWW = 56;
constexpr int HW  = HH * WWW;     // 3136
constexpr int CHW = ICC * HW;     // 802816
constexpr int TAPS = ICC * 9;     // 2304
constexpr int CAP  = 384;         // nnz per oc: mean ~230, sigma ~14
constexpr int XT = 14;            // x-tiles of 4
constexpr int YT = 14;            // y-tiles of 4
constexpr int NPB = 4;            // batches per block -> slab = 4n*6rows*256ic*56col*4B = 1.37MB < 4MB L2
constexpr int NG  = NB / NPB;     // 8 n-groups

struct __attribute__((packed)) f4p { float4 v; };

__global__ __launch_bounds__(64) void sparse_conv_slab(
    const float* __restrict__ in, const float* __restrict__ w,
    const float* __restrict__ bias, const int* __restrict__ mask,
    float* __restrict__ out)
{
  const int oc  = blockIdx.x;            // oc fastest: all 256 ocs of a slab adjacent in dispatch
  const int ng  = blockIdx.y / YT;
  const int yt  = blockIdx.y - ng * YT;  // y-tile uniform per block -> edge handling block-uniform
  const int tid = threadIdx.x;           // single wave

  __shared__ int2 s_tap[CAP];            // {meta, w-bits}; meta = ((soff+57)<<6)|(kh<<2)|kw

  // ---- tap compaction: 64 lanes x 4 ics each, wave-scan for positions (ic-ordered) ----
  int nn;
  {
    const int mbase = oc * TAPS + tid * 36;
    int c = 0;
    #pragma unroll
    for (int j = 0; j < 36; ++j) c += (mask[mbase + j] != 0) ? 1 : 0;
    int s = c;
    #pragma unroll
    for (int d = 1; d < 64; d <<= 1) { int o = __shfl_up(s, d, 64); if (tid >= d) s += o; }
    int pos = s - c;                     // exclusive prefix
    nn = __shfl(s, 63, 64);              // block total
    #pragma unroll
    for (int j = 0; j < 36; ++j) {
      if (mask[mbase + j] != 0) {
        const int ic = tid * 4 + j / 9;
        const int r9 = j - (j / 9) * 9;
        const int kh = r9 / 3, kw = r9 - kh * 3;
        const int soff = ic * HW + (kh - 1) * WWW + (kw - 1);
        s_tap[pos] = make_int2(((soff + 57) << 6) | (kh << 2) | kw,
                               __float_as_int(w[mbase + j]));
        ++pos;
      }
    }
    __syncthreads();
  }

  // ---- thread -> 4x4 output tile; lanes 56..63 shadow lane 55 (no store) ----
  const int te   = (tid < 56) ? tid : 55;
  const int nloc = te / XT;
  const int xg   = te - nloc * XT;
  const int n    = ng * NPB + nloc;
  const int y0   = yt * 4, x0 = xg * 4;

  const int ibase = n * CHW + y0 * WWW + x0;
  const int obase = (n * OCC + oc) * HW + y0 * WWW + x0;
  const float bv = bias[oc];

  float4 a0 = {bv,bv,bv,bv}, a1 = a0, a2 = a0, a3 = a0;

  const float fx0 = (xg == 0)      ? 0.f : 1.f;   // col -1 invalid
  const float fx3 = (xg == XT - 1) ? 0.f : 1.f;   // col 56 invalid

  const bool edgeblk = (yt == 0) || (yt == YT - 1);
  const bool danger  = (yt == 0      && n == 0      && xg == 0) ||
                       (yt == YT - 1 && n == NB - 1 && xg == XT - 1);

  if (!edgeblk) {
    // interior: rows y0-1..y0+4 valid, all addresses in-bounds -> maskless rows
    #pragma unroll 2
    for (int j = 0; j < nn; ++j) {
      const int2  t   = s_tap[j];
      const int   m   = __builtin_amdgcn_readfirstlane(t.x);
      const float val = __uint_as_float(__builtin_amdgcn_readfirstlane((unsigned)t.y));
      const int soff = (m >> 6) - 57;      // ic*HW + (kh-1)*W + (kw-1)  (scalar)
      const int kw   = m & 3;
      const float* p = in + (ibase + soff);
      const float4 v0 = ((const f4p*)(p          ))->v;
      const float4 v1 = ((const f4p*)(p +     WWW))->v;
      const float4 v2 = ((const f4p*)(p + 2 * WWW))->v;
      const float4 v3 = ((const f4p*)(p + 3 * WWW))->v;
      const float t0 = (kw == 0) ? val * fx0 : val;
      const float t3 = (kw == 2) ? val * fx3 : val;
      a0.x += t0 * v0.x; a0.y += val * v0.y; a0.z += val * v0.z; a0.w += t3 * v0.w;
      a1.x += t0 * v1.x; a1.y += val * v1.y; a1.z += val * v1.z; a1.w += t3 * v1.w;
      a2.x += t0 * v2.x; a2.y += val * v2.y; a2.z += val * v2.z; a2.w += t3 * v2.w;
      a3.x += t0 * v3.x; a3.y += val * v3.y; a3.z += val * v3.z; a3.w += t3 * v3.w;
    }
  } else if (!danger) {
    // y-edge blocks: per-row validity (at most one masked row per tap)
    for (int j = 0; j < nn; ++j) {
      const int2  t   = s_tap[j];
      const int   m   = __builtin_amdgcn_readfirstlane(t.x);
      const float val = __uint_as_float(__builtin_amdgcn_readfirstlane((unsigned)t.y));
      const int soff = (m >> 6) - 57;
      const int kh   = (m >> 2) & 3;
      const int kw   = m & 3;
      #pragma unroll
      for (int r = 0; r < 4; ++r) {
        const int row = y0 + r + kh - 1;
        const bool ok = (unsigned)row < (unsigned)HH;
        const int off = ok ? (ibase + soff + r * WWW) : 0;
        const float4 v = ((const f4p*)(in + off))->v;
        const float va = ok ? val : 0.f;
        const float t0 = (kw == 0) ? va * fx0 : va;
        const float t3 = (kw == 2) ? va * fx3 : va;
        float4* ar = (r == 0) ? &a0 : (r == 1) ? &a1 : (r == 2) ? &a2 : &a3;
        ar->x += t0 * v.x; ar->y += va * v.y; ar->z += va * v.z; ar->w += t3 * v.w;
      }
    }
  } else {
    // buffer-boundary lanes (first/last float4 of the tensor): fully guarded scalars
    for (int j = 0; j < nn; ++j) {
      const int2  t   = s_tap[j];
      const int   m   = t.x;
      const float val = __uint_as_float((unsigned)t.y);
      const int soff = (m >> 6) - 57;
      const int kh   = (m >> 2) & 3;
      const int kw   = m & 3;
      #pragma unroll
      for (int r = 0; r < 4; ++r) {
        const int row = y0 + r + kh - 1;
        const bool rok = (unsigned)row < (unsigned)HH;
        float4* ar = (r == 0) ? &a0 : (r == 1) ? &a1 : (r == 2) ? &a2 : &a3;
        #pragma unroll
        for (int e = 0; e < 4; ++e) {
          const int col = x0 + e + kw - 1;
          const bool ok = rok && ((unsigned)col < (unsigned)WWW);
          const int off = ok ? (ibase + soff + r * WWW + e) : 0;
          const float xv = in[off];
          const float tv = ok ? val : 0.f;
          if      (e == 0) ar->x += tv * xv;
          else if (e == 1) ar->y += tv * xv;
          else if (e == 2) ar->z += tv * xv;
          else             ar->w += tv * xv;
        }
      }
    }
  }

  if (tid < 56) {
    *(float4*)(out + obase          ) = a0;
    *(float4*)(out + obase +     WWW) = a1;
    *(float4*)(out + obase + 2 * WWW) = a2;
    *(float4*)(out + obase + 3 * WWW) = a3;
  }
}

extern "C" void kernel_launch(void* const* d_in, const int* in_sizes, int n_in,
                              void* d_out, int out_size, void* d_ws, size_t ws_size,
                              hipStream_t stream) {
  const float* in   = (const float*)d_in[0];
  const float* w    = (const float*)d_in[1];
  const float* bias = (const float*)d_in[2];
  const int*   mask = (const int*)d_in[3];
  float*       out  = (float*)d_out;

  dim3 grid(OCC, YT * NG);   // (256 oc) x (14 y-tiles * 8 n-groups) slabs
  sparse_conv_slab<<<grid, 64, 0, stream>>>(in, w, bias, mask, out);
}

// Round 4
// 368.814 us; speedup vs baseline: 5.7884x; 5.2706x over previous
//
#include <hip/hip_runtime.h>

// SparseConv2d N=32, OC=IC=256, H=W=56, K=3, pad=1 -> dense bf16 MFMA implicit GEMM
constexpr int NB=32, ICC=256, OCC=256, HH=56, WW=56;
constexpr int HW=HH*WW, CHW=ICC*HW;
constexpr int YT=14, MT=2;
constexpr int LROW=58;           // 56 cols + 2 halo
constexpr int PAD=36;            // ic slots per (r,c): 32 data + 4 pad (72B stride -> 2-way banks)
constexpr int LDS_ELEMS=6*LROW*PAD;   // 12528 ushort = 25056 B

using short8  = __attribute__((ext_vector_type(8))) short;   // 8 x bf16 bits (A/B frag)
using short4v = __attribute__((ext_vector_type(4))) short;
using f32x4   = __attribute__((ext_vector_type(4))) float;   // C/D frag

__device__ inline unsigned bf16rne(float x){
  unsigned u = __float_as_uint(x);
  return (u + 0x7fffu + ((u>>16)&1u)) >> 16;   // round-to-nearest-even
}

// wb[j][oc][ic] bf16, j = kh*3+kw, masked weights. 1.18 MB in d_ws.
__global__ __launch_bounds__(256) void pack_weights(
    const float* __restrict__ w, const int* __restrict__ mask,
    unsigned short* __restrict__ wb){
  const int oc = blockIdx.x, ic = threadIdx.x;
  const int base = (oc*ICC + ic)*9;
  #pragma unroll
  for (int j=0;j<9;++j){
    float v = (mask[base+j] != 0) ? w[base+j] : 0.f;
    wb[(j*OCC + oc)*ICC + ic] = (unsigned short)bf16rne(v);
  }
}

__global__ __launch_bounds__(256,2) void conv_mfma(
    const float* __restrict__ in, const unsigned short* __restrict__ wb,
    const float* __restrict__ bias, float* __restrict__ out){
  __shared__ unsigned short xt[LDS_ELEMS];   // [6 rows][58 cols][36 ic-slots]

  // XCD-aware decode: lid&7 = XCD residue -> each XCD sees only 4 of 32 batches
  const int lid  = blockIdx.x;
  const int xcd  = lid & 7, slot = lid >> 3;          // 112 slots per residue
  const int ngrp = slot / 28, rem = slot - ngrp*28;   // same-n blocks adjacent
  const int mt   = rem / 14,  yt  = rem - mt*14;
  const int n    = xcd + 8*ngrp;
  const int y0   = yt*4, ocb = mt*128;

  const int tid  = threadIdx.x;
  const int lane = tid & 63, wv = tid >> 6;
  const int q    = lane >> 4, l16 = lane & 15;

  // zero LDS once: halo cells (c=0, c=57, skipped rows) stay zero for all chunks
  for (int i = tid; i < LDS_ELEMS/2; i += 256) ((unsigned*)xt)[i] = 0u;

  // wave tile: 64 ocs x 112 px (4 x 7 MFMA tiles of 16x16)
  const int ocw = ocb + (wv & 1)*64;
  const int pxw = (wv >> 1)*112;

  int pbase[7];
  #pragma unroll
  for (int p=0;p<7;++p){
    int px = pxw + p*16 + l16;          // pixel within 4x56 tile (row-crossing OK)
    int yl = px / 56, x = px - yl*56;
    pbase[p] = (yl*LROW + x)*(PAD*2) + q*16;   // LDS byte addr, r=yl c=x, +kh/kw later
  }

  f32x4 acc[4][7];
  #pragma unroll
  for (int s=0;s<4;++s)
    #pragma unroll
    for (int p=0;p<7;++p) acc[s][p] = (f32x4){0.f,0.f,0.f,0.f};

  const int rskipA = (yt==0)      ? 0 : -1;   // input row y0-1 invalid
  const int rskipB = (yt==YT-1)   ? 5 : -1;   // input row y0+4 invalid

  __syncthreads();   // zeroing complete before first staging

  for (int ch=0; ch<8; ++ch){
    const int ic0 = ch*32;

    // ---- stage 32 ics x 6 rows x 56 cols fp32->bf16 into LDS ----
    // items: r(6) x xg(14) x icp(16), icp fastest (conflict-free ds_write_b32)
    #pragma unroll
    for (int i=0;i<6;++i){
      int idx = tid + i*256;
      if (idx < 1344){
        int r  = idx / 224;
        int r2 = idx - r*224;
        int xg = r2 >> 4, icp = r2 & 15;
        if (r != rskipA && r != rskipB){
          int y = y0 - 1 + r;
          const float* gp = in + n*CHW + (ic0 + icp*2)*HW + y*WW + xg*4;
          float4 g0 = *(const float4*)gp;          // ic plane
          float4 g1 = *(const float4*)(gp + HW);   // ic+1 plane
          unsigned w0 = bf16rne(g0.x) | (bf16rne(g1.x)<<16);
          unsigned w1 = bf16rne(g0.y) | (bf16rne(g1.y)<<16);
          unsigned w2 = bf16rne(g0.z) | (bf16rne(g1.z)<<16);
          unsigned w3 = bf16rne(g0.w) | (bf16rne(g1.w)<<16);
          unsigned* dp = (unsigned*)xt + (r*LROW + 1 + xg*4)*(PAD/2) + icp;
          dp[0]         = w0;            // col c=1+xg*4 .. +3, ic pair contiguous
          dp[PAD/2]     = w1;
          dp[PAD]       = w2;
          dp[3*(PAD/2)] = w3;
        }
      }
    }
    __syncthreads();

    // ---- K-slice: 9 offsets x 32 ics of MFMA ----
    #pragma unroll
    for (int kh=0;kh<3;++kh){
      #pragma unroll
      for (int kw=0;kw<3;++kw){
        const int j = kh*3 + kw;
        // A-frags: one contiguous 16B global load per oc-subtile (wave = 16 full lines)
        const unsigned short* wp = wb + (j*OCC + ocw + l16)*ICC + ic0 + q*8;
        short8 a0 = *(const short8*)(wp          );
        short8 a1 = *(const short8*)(wp + 16*ICC );
        short8 a2 = *(const short8*)(wp + 32*ICC );
        short8 a3 = *(const short8*)(wp + 48*ICC );
        const int doff = (kh*LROW + kw)*(PAD*2);   // shift within LDS tile
        #pragma unroll
        for (int p=0;p<7;++p){
          const char* bp = (const char*)xt + pbase[p] + doff;
          short4v blo = *(const short4v*)(bp    );   // ds_read_b64, 8B aligned
          short4v bhi = *(const short4v*)(bp + 8);
          short8 b = __builtin_shufflevector(blo, bhi, 0,1,2,3,4,5,6,7);
          acc[0][p] = __builtin_amdgcn_mfma_f32_16x16x32_bf16(a0, b, acc[0][p], 0,0,0);
          acc[1][p] = __builtin_amdgcn_mfma_f32_16x16x32_bf16(a1, b, acc[1][p], 0,0,0);
          acc[2][p] = __builtin_amdgcn_mfma_f32_16x16x32_bf16(a2, b, acc[2][p], 0,0,0);
          acc[3][p] = __builtin_amdgcn_mfma_f32_16x16x32_bf16(a3, b, acc[3][p], 0,0,0);
        }
      }
    }
    __syncthreads();
  }

  // ---- epilogue: D row = oc (quad*4+reg), col = px (lane&15)  [m89 layout] ----
  #pragma unroll
  for (int s=0;s<4;++s){
    const int oc4 = ocw + s*16 + q*4;
    float4 bv = *(const float4*)(bias + oc4);
    #pragma unroll
    for (int i=0;i<4;++i){
      const float bb = (i==0)?bv.x:(i==1)?bv.y:(i==2)?bv.z:bv.w;
      float* op = out + (n*OCC + oc4 + i)*HW + y0*WW + pxw + l16;
      #pragma unroll
      for (int p=0;p<7;++p){
        op[p*16] = acc[s][p][i] + bb;
      }
    }
  }
}

extern "C" void kernel_launch(void* const* d_in, const int* in_sizes, int n_in,
                              void* d_out, int out_size, void* d_ws, size_t ws_size,
                              hipStream_t stream) {
  const float* in   = (const float*)d_in[0];
  const float* w    = (const float*)d_in[1];
  const float* bias = (const float*)d_in[2];
  const int*   mask = (const int*)d_in[3];
  float*       out  = (float*)d_out;
  unsigned short* wb = (unsigned short*)d_ws;   // 9*256*256*2 B = 1.18 MB

  pack_weights<<<OCC, 256, 0, stream>>>(w, mask, wb);
  conv_mfma<<<8*4*MT*YT, 256, 0, stream>>>(in, wb, bias, out);  // 896 blocks
}